// Round 8
// baseline (451.367 us; speedup 1.0000x reference)
//
#include <hip/hip_runtime.h>
#include <math.h>

// ---------------------------------------------------------------------------
// D3AT transformer block on MI355X (gfx950), bf16 MFMA implementation.
// B=2, L=2048, C=1024, H=16, HD=64, FF=4096.
//
// R1: big GEMMs on 256x256 / 8-wave / BK=64 counted-vmcnt phase template.
// R2: flash softmax defer-max (T13); pre_kernel fusion.
// R3: gemm256 single-barrier phases.
// R4: out-proj -> gemm256 split-K=2 + fused reduce_oln.
// R5: flash v6 QBLK=256 (72us, was 148).
// R6: MLP2 atomics tried+reverted (cross-XCD L2 non-coherence -> HBM RMW).
// R7: gemm256 B-reg reuse (neutral -> phases are stall-bound, not LDS-bound).
//     flash Ps stride 80 (conflicts UP 6.3->7.3M) -> REVERTED in R8.
// R8: A/B experiment on gemm256 barrier structure: MLP1 runs gemm256_v2
//     with the learn_hip-template-exact phase (barrier -> lgkmcnt(0) ->
//     setprio MFMA -> barrier); QKV (identical 134MF/block K-loop) stays
//     on the single-barrier v1 as control. Separate __global__ to avoid
//     R2's cross-instantiation codegen poisoning (rule #19).
// ---------------------------------------------------------------------------

typedef __bf16 bf16;
typedef float f32x4 __attribute__((ext_vector_type(4)));
typedef bf16 bf16x8 __attribute__((ext_vector_type(8)));
typedef bf16 bf16x4 __attribute__((ext_vector_type(4)));

#define DEVINL __device__ __forceinline__

// log2(e): folded into Qc so flash softmax can use native exp2.
#define LOG2E 1.4426950408889634f

// NOTE: must not be named __exp2f — glibc math.h macro collision (round 7).
DEVINL float fast_exp2(float x) { return __builtin_amdgcn_exp2f(x); }

DEVINL void async_load16(const void* g, void* l) {
  __builtin_amdgcn_global_load_lds(
      (const __attribute__((address_space(1))) unsigned int*)g,
      (__attribute__((address_space(3))) unsigned int*)l, 16, 0, 0);
}

DEVINL f32x4 mfma16(bf16x8 a, bf16x8 b, f32x4 c) {
  return __builtin_amdgcn_mfma_f32_16x16x32_bf16(a, b, c, 0, 0, 0);
}

DEVINL float gelu_exact(float v) {
  return 0.5f * v * (1.0f + erff(v * 0.70710678118654752f));
}

// Raw barrier WITHOUT the compiler's vmcnt(0)-drain (__syncthreads would
// drain global_load_lds). Empty asm = compiler memory fences only.
DEVINL void hard_barrier() {
  asm volatile("" ::: "memory");
  __builtin_amdgcn_s_barrier();
  asm volatile("" ::: "memory");
}

DEVINL void block_reduce2(float& a, float& b, float* red, int tid) {
#pragma unroll
  for (int off = 32; off >= 1; off >>= 1) {
    a += __shfl_xor(a, off);
    b += __shfl_xor(b, off);
  }
  int w = tid >> 6;
  if ((tid & 63) == 0) { red[2 * w] = a; red[2 * w + 1] = b; }
  __syncthreads();
  a = red[0] + red[2] + red[4] + red[6];
  b = red[1] + red[3] + red[5] + red[7];
  __syncthreads();
}

// ---------------------------------------------------------------------------
// pre_kernel: all 4 weight transposes (fp32 -> bf16^T) + LN1/freq-MLP front
// half in ONE launch (all memory-bound; removes 4 launch gaps).
// blocks 0..12287: 32x32 transpose tiles; blocks 12288..16383: ln1 tokens.
// ---------------------------------------------------------------------------
__global__ __launch_bounds__(256) void pre_kernel(
    const float* __restrict__ qkv_w, const float* __restrict__ out_w,
    const float* __restrict__ mlp_w1, const float* __restrict__ mlp_w2,
    bf16* __restrict__ qkv_wt, bf16* __restrict__ out_wt,
    bf16* __restrict__ w1t, bf16* __restrict__ w2t,
    const float* __restrict__ x, const float* __restrict__ fd,
    const float* __restrict__ g1, const float* __restrict__ b1,
    const float* __restrict__ fw1, const float* __restrict__ fb1,
    const float* __restrict__ flg, const float* __restrict__ flb,
    bf16* __restrict__ xn, bf16* __restrict__ gout) {
  __shared__ float tile[32][33];
  __shared__ float red[8];
  const int id = blockIdx.x, t = threadIdx.x;
  if (id < 12288) {
    const float* W; bf16* Wt; int K, N, bx, by;
    if (id < 3072) {
      W = qkv_w; Wt = qkv_wt; K = 1024; N = 3072; bx = id % 96; by = id / 96;
    } else if (id < 4096) {
      int i = id - 3072;
      W = out_w; Wt = out_wt; K = 1024; N = 1024; bx = i & 31; by = i >> 5;
    } else if (id < 8192) {
      int i = id - 4096;
      W = mlp_w1; Wt = w1t; K = 1024; N = 4096; bx = i & 127; by = i >> 7;
    } else {
      int i = id - 8192;
      W = mlp_w2; Wt = w2t; K = 4096; N = 1024; bx = i & 31; by = i >> 5;
    }
    int n0 = bx * 32, k0 = by * 32;
    int tx = t & 31, ty = t >> 5;  // ty 0..7
#pragma unroll
    for (int r = 0; r < 4; ++r)
      tile[ty + r * 8][tx] = W[(size_t)(k0 + ty + r * 8) * N + n0 + tx];
    __syncthreads();
#pragma unroll
    for (int r = 0; r < 4; ++r)
      Wt[(size_t)(n0 + ty + r * 8) * K + k0 + tx] = (bf16)tile[tx][ty + r * 8];
    return;
  }
  // ---- ln1 + freq-bias scalar MLP front half (one block per token) ----
  int tok = id - 12288;
  float4 xv = ((const float4*)(x + (size_t)tok * 1024))[t];
  float s = xv.x + xv.y + xv.z + xv.w;
  float ss = xv.x * xv.x + xv.y * xv.y + xv.z * xv.z + xv.w * xv.w;
  block_reduce2(s, ss, red, t);
  float mean = s * (1.0f / 1024.0f);
  float rsig = rsqrtf(ss * (1.0f / 1024.0f) - mean * mean + 1e-5f);
  float4 g4 = ((const float4*)g1)[t], b4 = ((const float4*)b1)[t];
  bf16x4 o;
  o[0] = (bf16)((xv.x - mean) * rsig * g4.x + b4.x);
  o[1] = (bf16)((xv.y - mean) * rsig * g4.y + b4.y);
  o[2] = (bf16)((xv.z - mean) * rsig * g4.z + b4.z);
  o[3] = (bf16)((xv.w - mean) * rsig * g4.w + b4.w);
  ((bf16x4*)xn)[(size_t)tok * 256 + t] = o;

  float dv = fd[tok];
  float4 w4 = ((const float4*)fw1)[t], c4 = ((const float4*)fb1)[t];
  float f0 = dv * w4.x + c4.x, f1 = dv * w4.y + c4.y;
  float f2 = dv * w4.z + c4.z, f3 = dv * w4.w + c4.w;
  s = f0 + f1 + f2 + f3;
  ss = f0 * f0 + f1 * f1 + f2 * f2 + f3 * f3;
  block_reduce2(s, ss, red, t);
  mean = s * (1.0f / 1024.0f);
  rsig = rsqrtf(ss * (1.0f / 1024.0f) - mean * mean + 1e-5f);
  float4 lg = ((const float4*)flg)[t], lb = ((const float4*)flb)[t];
  bf16x4 q;
  q[0] = (bf16)gelu_exact((f0 - mean) * rsig * lg.x + lb.x);
  q[1] = (bf16)gelu_exact((f1 - mean) * rsig * lg.y + lb.y);
  q[2] = (bf16)gelu_exact((f2 - mean) * rsig * lg.z + lb.z);
  q[3] = (bf16)gelu_exact((f3 - mean) * rsig * lg.w + lb.w);
  ((bf16x4*)gout)[(size_t)tok * 256 + t] = q;
}

// ---------------------------------------------------------------------------
// prec_qk v2: fold fp_w2 with per-head wq_w/wk_w as a tiled block-diag GEMM.
// ---------------------------------------------------------------------------
__global__ __launch_bounds__(256) void prec_qk(
    const float* __restrict__ fp_w2, const float* __restrict__ fp_b2,
    const float* __restrict__ wq_w, const float* __restrict__ wq_b,
    const float* __restrict__ wk_w, const float* __restrict__ wk_b,
    bf16* __restrict__ wqk2t, float* __restrict__ bqk) {
  __shared__ float Wl[64 * 64];   // wsel[i][j]
  __shared__ float Al[64 * 128];  // fp_w2 chunk, [i][c] xor-swizzled
  const int id = blockIdx.x;
  const int sel = id >> 7, h = (id >> 3) & 15, ck = id & 7;
  const int t = threadIdx.x;
  const float* wsel = sel ? wk_w : wq_w;
#pragma unroll
  for (int i = 0; i < 4; ++i)
    ((float4*)Wl)[i * 256 + t] = ((const float4*)wsel)[i * 256 + t];
  const int c0 = ck * 128, off = h * 64;
#pragma unroll
  for (int it = 0; it < 8; ++it) {
    int idx = it * 256 + t;  // 0..2047
    int rr = idx >> 4, c4 = idx & 15;
    float4 v = *(const float4*)(fp_w2 + (size_t)(c0 + rr) * 1024 + off + c4 * 4);
    float vv[4] = {v.x, v.y, v.z, v.w};
#pragma unroll
    for (int k = 0; k < 4; ++k) {
      int i2 = c4 * 4 + k;
      Al[i2 * 128 + (rr ^ (i2 & 31))] = vv[k];
    }
  }
  __syncthreads();
  const int cr = t & 127, jh = (t >> 7) * 32;
  float acc[32];
#pragma unroll
  for (int j = 0; j < 32; ++j) acc[j] = 0.f;
  for (int i = 0; i < 64; ++i) {
    float a = Al[i * 128 + (cr ^ (i & 31))];
    const float4* wrow = (const float4*)(Wl + i * 64 + jh);
#pragma unroll
    for (int j4 = 0; j4 < 8; ++j4) {
      float4 wv = wrow[j4];
      acc[j4 * 4 + 0] += a * wv.x;
      acc[j4 * 4 + 1] += a * wv.y;
      acc[j4 * 4 + 2] += a * wv.z;
      acc[j4 * 4 + 3] += a * wv.w;
    }
  }
  const int nbase = sel * 1024 + off + jh;
#pragma unroll
  for (int j = 0; j < 32; ++j)
    wqk2t[(size_t)(nbase + j) * 1024 + c0 + cr] = (bf16)acc[j];
  if (ck == 0 && t < 64) {
    float s = 0.f;
    for (int i = 0; i < 64; ++i) s += fp_b2[off + i] * Wl[i * 64 + t];
    bqk[sel * 1024 + off + t] = s + (sel ? wk_b[t] : wq_b[t]);
  }
}

// ---------------------------------------------------------------------------
// reduce_oln: x1 = x + (op0 + op1) + out_b  (out-proj split-K partials),
// out0 = x1 + mlp_b2 (pre-init for MLP2 reduce), ln2 = bf16(LN(x1)).
// ---------------------------------------------------------------------------
__global__ __launch_bounds__(256) void reduce_oln(
    const float* __restrict__ part, const float* __restrict__ x,
    const float* __restrict__ outb, const float* __restrict__ b2,
    const float* __restrict__ g, const float* __restrict__ bb,
    float* __restrict__ out0, bf16* __restrict__ ln2) {
  __shared__ float red[8];
  int tok = blockIdx.x, t = threadIdx.x;
  size_t base = (size_t)tok * 256 + t;            // float4 index
  const size_t S = (size_t)4096 * 256;            // float4s per partial
  float4 p0 = ((const float4*)part)[base];
  float4 p1 = ((const float4*)part)[base + S];
  float4 xv = ((const float4*)x)[base];
  float4 ob = ((const float4*)outb)[t];
  float v0 = xv.x + p0.x + p1.x + ob.x;
  float v1 = xv.y + p0.y + p1.y + ob.y;
  float v2 = xv.z + p0.z + p1.z + ob.z;
  float v3 = xv.w + p0.w + p1.w + ob.w;
  float s = v0 + v1 + v2 + v3;
  float ss = v0 * v0 + v1 * v1 + v2 * v2 + v3 * v3;
  block_reduce2(s, ss, red, t);
  float mean = s * (1.0f / 1024.0f);
  float rsig = rsqrtf(ss * (1.0f / 1024.0f) - mean * mean + 1e-5f);
  float4 g4 = ((const float4*)g)[t], bb4 = ((const float4*)bb)[t];
  bf16x4 o;
  o[0] = (bf16)((v0 - mean) * rsig * g4.x + bb4.x);
  o[1] = (bf16)((v1 - mean) * rsig * g4.y + bb4.y);
  o[2] = (bf16)((v2 - mean) * rsig * g4.z + bb4.z);
  o[3] = (bf16)((v3 - mean) * rsig * g4.w + bb4.w);
  ((bf16x4*)ln2)[base] = o;
  float4 b24 = ((const float4*)b2)[t];
  float4 ov;
  ov.x = v0 + b24.x; ov.y = v1 + b24.y; ov.z = v2 + b24.z; ov.w = v3 + b24.w;
  ((float4*)out0)[base] = ov;
}

// ---------------------------------------------------------------------------
// 256x256 8-wave BK=64 GEMM, counted-vmcnt phase pipeline.
// v1 (PHASE): single barrier per phase (R3).
// v2 (PHASE2): learn_hip-template-exact: barrier -> lgkmcnt(0) -> setprio
//              MFMA -> barrier. A/B'd on MLP1 this round.
// B-half regs bfrA/bfrB: each B half loaded from LDS once per tile (R7).
// ---------------------------------------------------------------------------
#define PHASE_LOADS(MH, NH, LA, LB, BFR)                                      \
    if (LA) {                                                                 \
      _Pragma("unroll") for (int ml = 0; ml < 4; ++ml) {                      \
        _Pragma("unroll") for (int ks = 0; ks < 2; ++ks) {                    \
          const int rr = ml * 16 + lm;                                        \
          const int cc = (((ks * 4 + quad) ^ (lm & 7)) << 3);                 \
          af[ml][ks] = *(const bf16x8*)&As[bsel][MH][wm][rr][cc];             \
        }                                                                     \
      }                                                                       \
    }                                                                         \
    if (LB) {                                                                 \
      _Pragma("unroll") for (int nl = 0; nl < 2; ++nl) {                      \
        _Pragma("unroll") for (int ks = 0; ks < 2; ++ks) {                    \
          const int rr = nl * 16 + lm;                                        \
          const int cc = (((ks * 4 + quad) ^ (lm & 7)) << 3);                 \
          BFR[nl][ks] = *(const bf16x8*)&Bs[bsel][NH][wn][rr][cc];            \
        }                                                                     \
      }                                                                       \
    }

#define PHASE_MFMA(MH, NH, BFR)                                               \
    _Pragma("unroll") for (int ks = 0; ks < 2; ++ks) {                        \
      _Pragma("unroll") for (int ml = 0; ml < 4; ++ml) {                      \
        _Pragma("unroll") for (int nl = 0; nl < 2; ++nl) {                    \
          acc[(MH)*4 + ml][(NH)*2 + nl] = mfma16(                             \
              af[ml][ks], BFR[nl][ks], acc[(MH)*4 + ml][(NH)*2 + nl]);        \
        }                                                                     \
      }                                                                       \
    }

#define PHASE(MH, NH, LA, LB, BFR, STAGE_STMT, WAIT_STMT)                     \
  do {                                                                        \
    PHASE_LOADS(MH, NH, LA, LB, BFR)                                          \
    STAGE_STMT;                                                               \
    WAIT_STMT;                                                                \
    hard_barrier();                                                           \
    __builtin_amdgcn_s_setprio(1);                                            \
    PHASE_MFMA(MH, NH, BFR)                                                   \
    __builtin_amdgcn_s_setprio(0);                                            \
  } while (0)

#define PHASE2(MH, NH, LA, LB, BFR, STAGE_STMT, WAIT_STMT)                    \
  do {                                                                        \
    PHASE_LOADS(MH, NH, LA, LB, BFR)                                          \
    STAGE_STMT;                                                               \
    WAIT_STMT;                                                                \
    hard_barrier();                                                           \
    asm volatile("s_waitcnt lgkmcnt(0)" ::: "memory");                        \
    __builtin_amdgcn_s_setprio(1);                                            \
    PHASE_MFMA(MH, NH, BFR)                                                   \
    __builtin_amdgcn_s_setprio(0);                                            \
    hard_barrier();                                                           \
  } while (0)

#define GEMM256_BODY(PHASEM)                                                  \
  __shared__ __align__(16) bf16 As[2][2][2][64][64];                          \
  __shared__ __align__(16) bf16 Bs[2][2][4][32][64];                          \
  const int tid = threadIdx.x;                                                \
  const int lane = tid & 63, w = tid >> 6;                                    \
  const int quad = lane >> 4, lm = lane & 15;                                 \
  const int wm = w >> 2, wn = w & 3;                                          \
  const int kz = blockIdx.x / nblk;                                           \
  const int bid = blockIdx.x - kz * nblk;                                     \
  const int swz = (nblk & 7) ? bid : ((bid & 7) * (nblk >> 3) + (bid >> 3));  \
  const int tm = swz / nbx, tn = swz - tm * nbx;                              \
  const int m0 = tm << 8, n0 = tn << 8;                                       \
  const int rowoff = kz * rowoffz;                                            \
  A += (size_t)kz * kstride;                                                  \
  Bt += (size_t)kz * kstride;                                                 \
  const bf16* Abase = A + (size_t)m0 * lda;                                   \
  const bf16* Bbase = Bt + (size_t)n0 * ldb;                                  \
  auto stageA = [&](int b, int mh, int kt) {                                  \
    _Pragma("unroll") for (int j = 0; j < 2; ++j) {                           \
      const int q = (w * 2 + j) * 64 + lane;                                  \
      const int wm2 = q >> 9, rr = (q >> 3) & 63, c = q & 7;                  \
      async_load16(Abase + (size_t)(wm2 * 128 + mh * 64 + rr) * lda +         \
                       (size_t)kt * 64 + ((c ^ (rr & 7)) << 3),               \
                   (char*)&As[b][mh][0][0][0] + (w * 2 + j) * 1024);          \
    }                                                                         \
  };                                                                          \
  auto stageB = [&](int b, int nh, int kt) {                                  \
    _Pragma("unroll") for (int j = 0; j < 2; ++j) {                           \
      const int q = (w * 2 + j) * 64 + lane;                                  \
      const int wn4 = q >> 8, rr = (q >> 3) & 31, c = q & 7;                  \
      async_load16(Bbase + (size_t)(wn4 * 64 + nh * 32 + rr) * ldb +          \
                       (size_t)kt * 64 + ((c ^ (rr & 7)) << 3),               \
                   (char*)&Bs[b][nh][0][0][0] + (w * 2 + j) * 1024);          \
    }                                                                         \
  };                                                                          \
  f32x4 acc[8][4];                                                            \
  _Pragma("unroll") for (int i = 0; i < 8; ++i)                               \
    _Pragma("unroll") for (int j = 0; j < 4; ++j) {                           \
      acc[i][j][0] = 0.f; acc[i][j][1] = 0.f;                                 \
      acc[i][j][2] = 0.f; acc[i][j][3] = 0.f;                                 \
    }                                                                         \
  bf16x8 af[4][2], bfrA[2][2], bfrB[2][2];                                    \
  stageA(0, 0, 0); stageB(0, 1, 0); stageA(0, 1, 0); stageB(0, 0, 0);         \
  stageA(1, 0, 1); stageB(1, 1, 1);                                           \
  asm volatile("s_waitcnt vmcnt(4)" ::: "memory");                            \
  hard_barrier();                                                             \
  const int nt = K >> 6;                                                      \
  int bsel = 0;                                                               \
  for (int t = 0; t < nt; ++t, bsel ^= 1) {                                   \
    PHASEM(0, 0, 1, 1, bfrA, { if (t + 1 < nt) stageA(bsel ^ 1, 1, t + 1); }, {}); \
    PHASEM(0, 1, 0, 1, bfrB, { if (t + 1 < nt) stageB(bsel ^ 1, 0, t + 1); }, {}); \
    PHASEM(1, 1, 1, 0, bfrB, { if (t + 2 < nt) stageA(bsel, 0, t + 2); }, {});     \
    PHASEM(1, 0, 0, 0, bfrA, { if (t + 2 < nt) stageB(bsel, 1, t + 2); },          \
          {                                                                   \
            if (t + 2 < nt) {                                                 \
              asm volatile("s_waitcnt vmcnt(4)" ::: "memory");                \
            } else if (t + 1 < nt) {                                          \
              asm volatile("s_waitcnt vmcnt(0)" ::: "memory");                \
            }                                                                 \
          });                                                                 \
  }                                                                           \
  _Pragma("unroll") for (int mi = 0; mi < 8; ++mi)                            \
    _Pragma("unroll") for (int ni = 0; ni < 4; ++ni)                          \
      epi(rowoff + m0 + wm * 128 + mi * 16 + quad * 4,                        \
          n0 + wn * 64 + ni * 16 + lm, acc[mi][ni]);

template <class Epi>
__global__ __launch_bounds__(512, 2) void gemm256(
    const bf16* __restrict__ A, const bf16* __restrict__ Bt,
    int lda, int ldb, int K, int kstride, int nbx, int nblk, int rowoffz,
    Epi epi) {
  GEMM256_BODY(PHASE)
}

// v2: template-exact two-barrier phases; MLP1 only (A/B vs v1 on QKV).
template <class Epi>
__global__ __launch_bounds__(512, 2) void gemm256_v2(
    const bf16* __restrict__ A, const bf16* __restrict__ Bt,
    int lda, int ldb, int K, int kstride, int nbx, int nblk, int rowoffz,
    Epi epi) {
  GEMM256_BODY(PHASE2)
}

// out += part0 + part1 + part2 + part3  (out pre-initialized x1 + mlp_b2)
__global__ __launch_bounds__(256) void reduce_mlp2(
    const float* __restrict__ part, float* __restrict__ out) {
  size_t i = (size_t)blockIdx.x * 256 + threadIdx.x;  // float4 index
  const float4* p = (const float4*)part;
  float4 o = ((const float4*)out)[i];
  const size_t S = (size_t)4096 * 256;  // float4s per partial
  float4 a = p[i], b = p[i + S], c = p[i + 2 * S], d = p[i + 3 * S];
  o.x += a.x + b.x + c.x + d.x;
  o.y += a.y + b.y + c.y + d.y;
  o.z += a.z + b.z + c.z + d.z;
  o.w += a.w + b.w + c.w + d.w;
  ((float4*)out)[i] = o;
}

// --------------------------- epilogue functors -----------------------------
// Qc carries log2e so flash softmax can use native exp2.
struct EpiQKV {
  const float* __restrict__ bias;
  bf16 *Qc, *Kc, *Vt;
  DEVINL void operator()(int row, int col, f32x4 v) const {
    int b = row >> 11, l = row & 2047;
    float bia = bias[col];
    if (col < 1024) {
      int h = col >> 6, d = col & 63;
      bf16* p = Qc + (size_t)(((b << 4) + h) * 2048 + l) * 128 + d;
#pragma unroll
      for (int r = 0; r < 4; ++r) p[r * 128] = (bf16)((v[r] + bia) * (0.125f * LOG2E));
    } else if (col < 2048) {
      int c2 = col - 1024, h = c2 >> 6, d = c2 & 63;
      bf16* p = Kc + (size_t)(((b << 4) + h) * 2048 + l) * 128 + d;
#pragma unroll
      for (int r = 0; r < 4; ++r) p[r * 128] = (bf16)(v[r] + bia);
    } else {
      int c2 = col - 2048, h = c2 >> 6, d = c2 & 63;
      bf16x4 pk;
#pragma unroll
      for (int r = 0; r < 4; ++r) pk[r] = (bf16)(v[r] + bia);
      *(bf16x4*)(Vt + (size_t)(((b << 4) + h) * 64 + d) * 2048 + l) = pk;
    }
  }
};

struct EpiQBKB {
  const float* __restrict__ bias;
  const float* __restrict__ fs;
  bf16 *Qc, *Kc;
  DEVINL void operator()(int row, int col, f32x4 v) const {
    int b = row >> 11, l = row & 2047;
    float bia = bias[col];
    if (col < 1024) {
      int h = col >> 6, d = col & 63;
      float sc = fs[0] * LOG2E;
      bf16* p = Qc + (size_t)(((b << 4) + h) * 2048 + l) * 128 + 64 + d;
#pragma unroll
      for (int r = 0; r < 4; ++r) p[r * 128] = (bf16)((v[r] + bia) * sc);
    } else {
      int c2 = col - 1024, h = c2 >> 6, d = c2 & 63;
      bf16* p = Kc + (size_t)(((b << 4) + h) * 2048 + l) * 128 + 64 + d;
#pragma unroll
      for (int r = 0; r < 4; ++r) p[r * 128] = (bf16)(v[r] + bia);
    }
  }
};

struct EpiMLP1 {
  const float* __restrict__ bias;
  bf16* hbf;
  DEVINL void operator()(int row, int col, f32x4 v) const {
    float bia = bias[col];
#pragma unroll
    for (int r = 0; r < 4; ++r)
      hbf[(size_t)(row + r) * 4096 + col] = (bf16)gelu_exact(v[r] + bia);
  }
};

// split-K partials: row already carries kz*4096 offset.
struct EpiPart {
  float* part;
  DEVINL void operator()(int row, int col, f32x4 v) const {
#pragma unroll
    for (int r = 0; r < 4; ++r)
      part[(size_t)(row + r) * 1024 + col] = v[r];
  }
};

// ---------------------------------------------------------------------------
// Flash attention v6.2 (R8): QBLK=256 + T5 setprio; Ps stride reverted to
// 64 (R7's stride-80 experiment INCREASED conflicts 6.3->7.3M).
// ---------------------------------------------------------------------------
#define PSS 64  // Ps row stride in bf16

__global__ __launch_bounds__(512, 2) void flash_kernel(
    const bf16* __restrict__ Qc, const bf16* __restrict__ Kcp,
    const bf16* __restrict__ Vt, bf16* __restrict__ Obf) {
  __shared__ bf16 KsA[64 * 128];
  __shared__ bf16 KsB[64 * 128];
  __shared__ bf16 VsA[64 * 64];
  __shared__ bf16 VsB[64 * 64];
  __shared__ bf16 Ps[256 * PSS];  // P^T rows=q; per-wave private rows

  const int tid = threadIdx.x, lane = tid & 63, w = tid >> 6;  // w 0..7
  const int quad = lane >> 4, lm = lane & 15;
  const int id = blockIdx.x;
  const int bh = id & 31, qt = id >> 5;  // qt 0..7
  const int b = bh >> 4, h = bh & 15;
  const int qrw = w * 32;                // wave's first q row in 256-row tile

  const bf16* Kg0 = Kcp + (size_t)bh * 2048 * 128;
  const bf16* Vg0 = Vt + (size_t)bh * 64 * 2048;

  auto stage = [&](int kv, bf16* Kdst, bf16* Vdst) {
    const bf16* Kg = Kg0 + (size_t)kv * 64 * 128;
#pragma unroll
    for (int i = 0; i < 2; ++i) {
      int ch = i * 512 + tid, key = ch >> 4, c = (ch & 15) ^ (key & 7);
      async_load16(Kg + (size_t)key * 128 + c * 8,
                   (char*)Kdst + (i * 512 + w * 64) * 16);
    }
    {
      int d = tid >> 3, c = (tid & 7) ^ (d & 7);
      async_load16(Vg0 + (size_t)d * 2048 + kv * 64 + c * 8,
                   (char*)Vdst + (w * 64) * 16);
    }
  };

  stage(0, KsA, VsA);  // issue tile-0 DMA first; Q reg loads overlap it

  // ---- Q fragments, ONCE, direct global -> registers ----
  const bf16* Qg = Qc + ((size_t)bh * 2048 + qt * 256) * 128;
  bf16x8 qf[2][4];
#pragma unroll
  for (int qh = 0; qh < 2; ++qh)
#pragma unroll
    for (int ks = 0; ks < 4; ++ks)
      qf[qh][ks] = *(const bf16x8*)(Qg + (size_t)(qrw + qh * 16 + lm) * 128 +
                                    (ks * 4 + quad) * 8);

  float m_run[2] = {-3.0e38f, -3.0e38f};
  float l_lane[2] = {0.f, 0.f};
  f32x4 o_acc[2][4];
#pragma unroll
  for (int qh = 0; qh < 2; ++qh)
#pragma unroll
    for (int nf = 0; nf < 4; ++nf) {
      o_acc[qh][nf][0] = 0.f; o_acc[qh][nf][1] = 0.f;
      o_acc[qh][nf][2] = 0.f; o_acc[qh][nf][3] = 0.f;
    }

  for (int kv = 0; kv < 32; ++kv) {
    const bf16* Kcur = (kv & 1) ? KsB : KsA;
    const bf16* Vcur = (kv & 1) ? VsB : VsA;
    __syncthreads();  // drains stage(kv); prev reads of other buf done
    if (kv + 1 < 32)
      stage(kv + 1, (kv & 1) ? KsA : KsB, (kv & 1) ? VsA : VsB);

    // ---- S^T = K · Q^T : 64 keys x 32 q (2 halves share ak reads) ----
    f32x4 sa[2][4];
#pragma unroll
    for (int qh = 0; qh < 2; ++qh)
#pragma unroll
      for (int nk = 0; nk < 4; ++nk) {
        sa[qh][nk][0] = 0.f; sa[qh][nk][1] = 0.f;
        sa[qh][nk][2] = 0.f; sa[qh][nk][3] = 0.f;
      }
    __builtin_amdgcn_s_setprio(1);
#pragma unroll
    for (int ks = 0; ks < 4; ++ks) {
      bf16x8 ak[4];
#pragma unroll
      for (int nk = 0; nk < 4; ++nk) {
        int key = nk * 16 + lm;
        int pos = (ks * 4 + quad) ^ (key & 7);
        ak[nk] = *(const bf16x8*)(Kcur + key * 128 + pos * 8);
      }
#pragma unroll
      for (int nk = 0; nk < 4; ++nk) {
        sa[0][nk] = mfma16(ak[nk], qf[0][ks], sa[0][nk]);
        sa[1][nk] = mfma16(ak[nk], qf[1][ks], sa[1][nk]);
      }
    }
    __builtin_amdgcn_s_setprio(0);

#pragma unroll
    for (int qh = 0; qh < 2; ++qh) {
      // ---- online softmax (exp2 domain); lane owns column qrw+qh*16+lm ----
      float mx = fmaxf(fmaxf(sa[qh][0][0], sa[qh][0][1]), sa[qh][0][2]);
      mx = fmaxf(fmaxf(mx, sa[qh][0][3]), sa[qh][1][0]);
      mx = fmaxf(fmaxf(mx, sa[qh][1][1]), sa[qh][1][2]);
      mx = fmaxf(fmaxf(mx, sa[qh][1][3]), sa[qh][2][0]);
      mx = fmaxf(fmaxf(mx, sa[qh][2][1]), sa[qh][2][2]);
      mx = fmaxf(fmaxf(mx, sa[qh][2][3]), sa[qh][3][0]);
      mx = fmaxf(fmaxf(mx, sa[qh][3][1]), sa[qh][3][2]);
      mx = fmaxf(mx, sa[qh][3][3]);
      mx = fmaxf(mx, __shfl_xor(mx, 16));
      mx = fmaxf(mx, __shfl_xor(mx, 32));
      // defer-max: only rescale when some lane's max grew past m_run + 8.
      if (__any(mx > m_run[qh] + 8.0f)) {
        float mnew = fmaxf(m_run[qh], mx);
        float alpha = fast_exp2(m_run[qh] - mnew);
        m_run[qh] = mnew;
        l_lane[qh] *= alpha;
#pragma unroll
        for (int nf = 0; nf < 4; ++nf) {
          o_acc[qh][nf][0] *= alpha; o_acc[qh][nf][1] *= alpha;
          o_acc[qh][nf][2] *= alpha; o_acc[qh][nf][3] *= alpha;
        }
      }
      float rs = 0.f;
#pragma unroll
      for (int nk = 0; nk < 4; ++nk)
#pragma unroll
        for (int rg = 0; rg < 4; ++rg) {
          float pv = fast_exp2(sa[qh][nk][rg] - m_run[qh]);
          sa[qh][nk][rg] = pv;
          rs += pv;
        }
      l_lane[qh] += rs;  // cross-quad reduce deferred past the kv loop

      // ---- write P^T rows (wave-private; same-wave readback) ----
      int qr = qrw + qh * 16 + lm;
#pragma unroll
      for (int nk = 0; nk < 4; ++nk) {
        int c16 = 2 * nk + (quad >> 1);
        int cs = c16 ^ (lm & 7);
        bf16x4 pk;
        pk[0] = (bf16)sa[qh][nk][0]; pk[1] = (bf16)sa[qh][nk][1];
        pk[2] = (bf16)sa[qh][nk][2]; pk[3] = (bf16)sa[qh][nk][3];
        *(bf16x4*)(Ps + qr * PSS + cs * 8 + (quad & 1) * 4) = pk;
      }
    }

    // ---- O^T += V^T · P^T (vb reads shared across both q-halves) ----
#pragma unroll
    for (int ks = 0; ks < 2; ++ks) {
      bf16x8 vb[4], pa[2];
#pragma unroll
      for (int nf = 0; nf < 4; ++nf) {
        int d = nf * 16 + lm;
        int cs = (ks * 4 + quad) ^ (d & 7);
        vb[nf] = *(const bf16x8*)(Vcur + d * 64 + cs * 8);
      }
#pragma unroll
      for (int qh = 0; qh < 2; ++qh) {
        int qr = qrw + qh * 16 + lm;
        int cs = (ks * 4 + quad) ^ (lm & 7);
        pa[qh] = *(const bf16x8*)(Ps + qr * PSS + cs * 8);
      }
      __builtin_amdgcn_s_setprio(1);
#pragma unroll
      for (int qh = 0; qh < 2; ++qh)
#pragma unroll
        for (int nf = 0; nf < 4; ++nf)
          o_acc[qh][nf] = mfma16(vb[nf], pa[qh], o_acc[qh][nf]);
      __builtin_amdgcn_s_setprio(0);
    }
  }

  // ---- normalize (in-lane after final cross-quad l reduce) + write O ----
#pragma unroll
  for (int qh = 0; qh < 2; ++qh) {
    float lt = l_lane[qh];
    lt += __shfl_xor(lt, 16);
    lt += __shfl_xor(lt, 32);
    float inv = 1.0f / lt;
    int l = qt * 256 + qrw + qh * 16 + lm;
#pragma unroll
    for (int nf = 0; nf < 4; ++nf) {
      bf16x4 ov;
#pragma unroll
      for (int rg = 0; rg < 4; ++rg) ov[rg] = (bf16)(o_acc[qh][nf][rg] * inv);
      int d = h * 64 + nf * 16 + quad * 4;
      *(bf16x4*)(Obf + ((size_t)b * 2048 + l) * 1024 + d) = ov;
    }
  }
}

// ---------------------------------------------------------------------------
extern "C" void kernel_launch(void* const* d_in, const int* in_sizes, int n_in,
                              void* d_out, int out_size, void* d_ws, size_t ws_size,
                              hipStream_t stream) {
  (void)in_sizes; (void)n_in; (void)out_size; (void)ws_size;
  const float* x      = (const float*)d_in[0];
  const float* fd     = (const float*)d_in[1];
  const float* qkv_w  = (const float*)d_in[2];
  const float* qkv_b  = (const float*)d_in[3];
  const float* fp_w1  = (const float*)d_in[4];
  const float* fp_b1  = (const float*)d_in[5];
  const float* fp_ln_g= (const float*)d_in[6];
  const float* fp_ln_b= (const float*)d_in[7];
  const float* fp_w2  = (const float*)d_in[8];
  const float* fp_b2  = (const float*)d_in[9];
  const float* wq_w   = (const float*)d_in[10];
  const float* wq_b   = (const float*)d_in[11];
  const float* wk_w   = (const float*)d_in[12];
  const float* wk_b   = (const float*)d_in[13];
  const float* out_w  = (const float*)d_in[14];
  const float* out_b  = (const float*)d_in[15];
  const float* n1_g   = (const float*)d_in[16];
  const float* n1_b   = (const float*)d_in[17];
  const float* n2_g   = (const float*)d_in[18];
  const float* n2_b   = (const float*)d_in[19];
  const float* mlp_w1 = (const float*)d_in[20];
  const float* mlp_b1 = (const float*)d_in[21];
  const float* mlp_w2 = (const float*)d_in[22];
  const float* mlp_b2 = (const float*)d_in[23];
  const float* fscale = (const float*)d_in[24];
  float* out = (float*)d_out;

  char* p = (char*)d_ws;
  auto take = [&](size_t n) { char* r = p; p += (n + 255) & ~(size_t)255; return r; };
  bf16* xn_bf  = (bf16*)take((size_t)4096 * 1024 * 2);
  bf16* g_bf   = (bf16*)take((size_t)4096 * 1024 * 2);
  bf16* Qc     = (bf16*)take((size_t)32 * 2048 * 128 * 2);
  bf16* Kc     = (bf16*)take((size_t)32 * 2048 * 128 * 2);
  bf16* Vt     = (bf16*)take((size_t)32 * 64 * 2048 * 2);
  bf16* o_bf   = (bf16*)take((size_t)4096 * 1024 * 2);
  bf16* ln2_bf = (bf16*)take((size_t)4096 * 1024 * 2);
  bf16* h_bf   = (bf16*)take((size_t)4096 * 4096 * 2);
  bf16* qkv_wt = (bf16*)take((size_t)3072 * 1024 * 2);
  bf16* out_wt = (bf16*)take((size_t)1024 * 1024 * 2);
  bf16* w1t    = (bf16*)take((size_t)4096 * 1024 * 2);
  bf16* w2t    = (bf16*)take((size_t)1024 * 4096 * 2);
  bf16* wqk2t  = (bf16*)take((size_t)2048 * 1024 * 2);
  float* bqk   = (float*)take((size_t)2048 * 4);

  // MLP2 partials (4 x 16 MB fp32) alias the dead xn/g/Qc/Kc/Vt region.
  float* part = (float*)xn_bf;
  // out-proj partials (2 x 16 MB fp32) alias h_bf (written later by MLP1;
  // opart is dead before MLP1 runs).
  float* opart = (float*)h_bf;

  dim3 b256(256), b512(512);

  prec_qk<<<dim3(256), b256, 0, stream>>>(fp_w2, fp_b2, wq_w, wq_b, wk_w, wk_b, wqk2t, bqk);
  // all 4 weight transposes + ln1 in one launch (12288 + 4096 blocks)
  pre_kernel<<<dim3(16384), b256, 0, stream>>>(
      qkv_w, out_w, mlp_w1, mlp_w2, qkv_wt, out_wt, w1t, w2t,
      x, fd, n1_g, n1_b, fp_w1, fp_b1, fp_ln_g, fp_ln_b, xn_bf, g_bf);

  // QKV: M=4096 N=3072 K=1024 -> 12x16 = 192 blocks (v1, control)
  gemm256<<<dim3(192), b512, 0, stream>>>(xn_bf, qkv_wt, 1024, 1024, 1024, 0,
                                          12, 192, 0, EpiQKV{qkv_b, Qc, Kc, Vt});
  // QB/KB: M=4096 N=2048 K=1024 -> 8x16 = 128 blocks
  gemm256<<<dim3(128), b512, 0, stream>>>(g_bf, wqk2t, 1024, 1024, 1024, 0,
                                          8, 128, 0, EpiQBKB{bqk, fscale, Qc, Kc});
  // flash: 32 bh x 8 q-tiles (QBLK=256) = 256 blocks
  flash_kernel<<<dim3(256), dim3(512), 0, stream>>>(Qc, Kc, Vt, o_bf);

  // out-proj split-K=2: per kz 16x4 = 64 blocks; partials -> reduce_oln.
  gemm256<<<dim3(128), b512, 0, stream>>>(o_bf, out_wt, 1024, 1024, 512, 512,
                                          4, 64, 4096, EpiPart{opart});
  // residual + bias + LN2 + out0-preinit fused (out0 = x1 + mlp_b2)
  reduce_oln<<<dim3(4096), b256, 0, stream>>>(opart, x, out_b, mlp_b2,
                                              n2_g, n2_b, out, ln2_bf);
  // MLP1: M=4096 N=4096 K=1024 -> 256 blocks (v2, two-barrier EXPERIMENT)
  gemm256_v2<<<dim3(256), b512, 0, stream>>>(ln2_bf, w1t, 1024, 1024, 1024, 0,
                                             16, 256, 0, EpiMLP1{mlp_b1, h_bf});
  // MLP2 split-K=4: per split M=4096 N=1024 K=1024 -> 4x16 = 64 blocks, x4
  gemm256<<<dim3(256), b512, 0, stream>>>(h_bf, w2t, 4096, 4096, 1024, 1024,
                                          4, 64, 4096, EpiPart{part});
  reduce_mlp2<<<dim3(4096), b256, 0, stream>>>(part, out);
}

// Round 9
// 444.298 us; speedup vs baseline: 1.0159x; 1.0159x over previous
//
#include <hip/hip_runtime.h>
#include <math.h>

// ---------------------------------------------------------------------------
// D3AT transformer block on MI355X (gfx950), bf16 MFMA implementation.
// B=2, L=2048, C=1024, H=16, HD=64, FF=4096.
//
// R1: big GEMMs on 256x256 / 8-wave / BK=64 counted-vmcnt phase template.
// R2: flash softmax defer-max (T13); pre_kernel fusion.
// R3: gemm256 single-barrier phases.
// R4: out-proj -> gemm256 split-K=2 + fused reduce_oln.
// R5: flash v6 QBLK=256 (72us, was 148).
// R6: MLP2 atomics tried+reverted (cross-XCD L2 non-coherence -> HBM RMW).
// R7: gemm256 B-reg reuse (neutral); flash Ps stride 80 (reverted).
// R8: two-barrier phase A/B on MLP1: -5us -> single-barrier CONFIRMED.
// R9: consolidation: MLP1 back to v1 (v2 deleted); prec_qk merged into
//     pre_kernel (one launch, prec blocks first). GEMM inner loop declared
//     converged: 256^2 tile needs ~236 VGPR+AGPR/wave -> 2 blocks/CU is
//     impossible; all catalog levers applied (conflicts=0, counted vmcnt,
//     setprio, 1-barrier); residual gap vs reference is asm-level sched.
// ---------------------------------------------------------------------------

typedef __bf16 bf16;
typedef float f32x4 __attribute__((ext_vector_type(4)));
typedef bf16 bf16x8 __attribute__((ext_vector_type(8)));
typedef bf16 bf16x4 __attribute__((ext_vector_type(4)));

#define DEVINL __device__ __forceinline__

// log2(e): folded into Qc so flash softmax can use native exp2.
#define LOG2E 1.4426950408889634f

// NOTE: must not be named __exp2f — glibc math.h macro collision (round 7).
DEVINL float fast_exp2(float x) { return __builtin_amdgcn_exp2f(x); }

DEVINL void async_load16(const void* g, void* l) {
  __builtin_amdgcn_global_load_lds(
      (const __attribute__((address_space(1))) unsigned int*)g,
      (__attribute__((address_space(3))) unsigned int*)l, 16, 0, 0);
}

DEVINL f32x4 mfma16(bf16x8 a, bf16x8 b, f32x4 c) {
  return __builtin_amdgcn_mfma_f32_16x16x32_bf16(a, b, c, 0, 0, 0);
}

DEVINL float gelu_exact(float v) {
  return 0.5f * v * (1.0f + erff(v * 0.70710678118654752f));
}

// Raw barrier WITHOUT the compiler's vmcnt(0)-drain (__syncthreads would
// drain global_load_lds). Empty asm = compiler memory fences only.
DEVINL void hard_barrier() {
  asm volatile("" ::: "memory");
  __builtin_amdgcn_s_barrier();
  asm volatile("" ::: "memory");
}

DEVINL void block_reduce2(float& a, float& b, float* red, int tid) {
#pragma unroll
  for (int off = 32; off >= 1; off >>= 1) {
    a += __shfl_xor(a, off);
    b += __shfl_xor(b, off);
  }
  int w = tid >> 6;
  if ((tid & 63) == 0) { red[2 * w] = a; red[2 * w + 1] = b; }
  __syncthreads();
  a = red[0] + red[2] + red[4] + red[6];
  b = red[1] + red[3] + red[5] + red[7];
  __syncthreads();
}

// ---------------------------------------------------------------------------
// pre_kernel v2 (R9): prec_qk (blocks 0..255) + 4 weight transposes
// (256..12543) + LN1/freq-MLP (12544..16639) in ONE launch. LDS unioned in
// one 48KB buffer (prec needs Wl 16KB + Al 32KB; transpose needs 4.2KB).
// prec blocks are first in the grid so wqk2t/bqk complete earliest.
// ---------------------------------------------------------------------------
__global__ __launch_bounds__(256) void pre_kernel(
    const float* __restrict__ fp_w2, const float* __restrict__ fp_b2,
    const float* __restrict__ wq_w, const float* __restrict__ wq_b,
    const float* __restrict__ wk_w, const float* __restrict__ wk_b,
    bf16* __restrict__ wqk2t, float* __restrict__ bqk,
    const float* __restrict__ qkv_w, const float* __restrict__ out_w,
    const float* __restrict__ mlp_w1, const float* __restrict__ mlp_w2,
    bf16* __restrict__ qkv_wt, bf16* __restrict__ out_wt,
    bf16* __restrict__ w1t, bf16* __restrict__ w2t,
    const float* __restrict__ x, const float* __restrict__ fd,
    const float* __restrict__ g1, const float* __restrict__ b1,
    const float* __restrict__ fw1, const float* __restrict__ fb1,
    const float* __restrict__ flg, const float* __restrict__ flb,
    bf16* __restrict__ xn, bf16* __restrict__ gout) {
  __shared__ __align__(16) char smem[49152];  // 48KB union
  const int id = blockIdx.x, t = threadIdx.x;

  if (id < 256) {
    // ---- prec_qk: fold fp_w2 with per-head wq_w/wk_w (block-diag GEMM) ----
    float* Wl = (float*)smem;                 // 64*64 = 16KB
    float* Al = (float*)(smem + 16384);       // 64*128 = 32KB
    const int sel = id >> 7, h = (id >> 3) & 15, ck = id & 7;
    const float* wsel = sel ? wk_w : wq_w;
#pragma unroll
    for (int i = 0; i < 4; ++i)
      ((float4*)Wl)[i * 256 + t] = ((const float4*)wsel)[i * 256 + t];
    const int c0 = ck * 128, off = h * 64;
#pragma unroll
    for (int it = 0; it < 8; ++it) {
      int idx = it * 256 + t;  // 0..2047
      int rr = idx >> 4, c4 = idx & 15;
      float4 v = *(const float4*)(fp_w2 + (size_t)(c0 + rr) * 1024 + off + c4 * 4);
      float vv[4] = {v.x, v.y, v.z, v.w};
#pragma unroll
      for (int k = 0; k < 4; ++k) {
        int i2 = c4 * 4 + k;
        Al[i2 * 128 + (rr ^ (i2 & 31))] = vv[k];
      }
    }
    __syncthreads();
    const int cr = t & 127, jh = (t >> 7) * 32;
    float acc[32];
#pragma unroll
    for (int j = 0; j < 32; ++j) acc[j] = 0.f;
    for (int i = 0; i < 64; ++i) {
      float a = Al[i * 128 + (cr ^ (i & 31))];
      const float4* wrow = (const float4*)(Wl + i * 64 + jh);
#pragma unroll
      for (int j4 = 0; j4 < 8; ++j4) {
        float4 wv = wrow[j4];
        acc[j4 * 4 + 0] += a * wv.x;
        acc[j4 * 4 + 1] += a * wv.y;
        acc[j4 * 4 + 2] += a * wv.z;
        acc[j4 * 4 + 3] += a * wv.w;
      }
    }
    const int nbase = sel * 1024 + off + jh;
#pragma unroll
    for (int j = 0; j < 32; ++j)
      wqk2t[(size_t)(nbase + j) * 1024 + c0 + cr] = (bf16)acc[j];
    if (ck == 0 && t < 64) {
      float s = 0.f;
      for (int i = 0; i < 64; ++i) s += fp_b2[off + i] * Wl[i * 64 + t];
      bqk[sel * 1024 + off + t] = s + (sel ? wk_b[t] : wq_b[t]);
    }
    return;
  }

  if (id < 12544) {
    // ---- weight transpose + cast: W[K][N] fp32 -> Wt[N][K] bf16 ----
    float (*tile)[33] = (float(*)[33])smem;   // 32*33*4 = 4.2KB
    int i0 = id - 256;
    const float* W; bf16* Wt; int K, N, bx, by;
    if (i0 < 3072) {
      W = qkv_w; Wt = qkv_wt; K = 1024; N = 3072; bx = i0 % 96; by = i0 / 96;
    } else if (i0 < 4096) {
      int i = i0 - 3072;
      W = out_w; Wt = out_wt; K = 1024; N = 1024; bx = i & 31; by = i >> 5;
    } else if (i0 < 8192) {
      int i = i0 - 4096;
      W = mlp_w1; Wt = w1t; K = 1024; N = 4096; bx = i & 127; by = i >> 7;
    } else {
      int i = i0 - 8192;
      W = mlp_w2; Wt = w2t; K = 4096; N = 1024; bx = i & 31; by = i >> 5;
    }
    int n0 = bx * 32, k0 = by * 32;
    int tx = t & 31, ty = t >> 5;  // ty 0..7
#pragma unroll
    for (int r = 0; r < 4; ++r)
      tile[ty + r * 8][tx] = W[(size_t)(k0 + ty + r * 8) * N + n0 + tx];
    __syncthreads();
#pragma unroll
    for (int r = 0; r < 4; ++r)
      Wt[(size_t)(n0 + ty + r * 8) * K + k0 + tx] = (bf16)tile[tx][ty + r * 8];
    return;
  }

  // ---- ln1 + freq-bias scalar MLP front half (one block per token) ----
  float* red = (float*)smem;
  int tok = id - 12544;
  float4 xv = ((const float4*)(x + (size_t)tok * 1024))[t];
  float s = xv.x + xv.y + xv.z + xv.w;
  float ss = xv.x * xv.x + xv.y * xv.y + xv.z * xv.z + xv.w * xv.w;
  block_reduce2(s, ss, red, t);
  float mean = s * (1.0f / 1024.0f);
  float rsig = rsqrtf(ss * (1.0f / 1024.0f) - mean * mean + 1e-5f);
  float4 g4 = ((const float4*)g1)[t], b4 = ((const float4*)b1)[t];
  bf16x4 o;
  o[0] = (bf16)((xv.x - mean) * rsig * g4.x + b4.x);
  o[1] = (bf16)((xv.y - mean) * rsig * g4.y + b4.y);
  o[2] = (bf16)((xv.z - mean) * rsig * g4.z + b4.z);
  o[3] = (bf16)((xv.w - mean) * rsig * g4.w + b4.w);
  ((bf16x4*)xn)[(size_t)tok * 256 + t] = o;

  float dv = fd[tok];
  float4 w4 = ((const float4*)fw1)[t], c4 = ((const float4*)fb1)[t];
  float f0 = dv * w4.x + c4.x, f1 = dv * w4.y + c4.y;
  float f2 = dv * w4.z + c4.z, f3 = dv * w4.w + c4.w;
  s = f0 + f1 + f2 + f3;
  ss = f0 * f0 + f1 * f1 + f2 * f2 + f3 * f3;
  block_reduce2(s, ss, red, t);
  mean = s * (1.0f / 1024.0f);
  rsig = rsqrtf(ss * (1.0f / 1024.0f) - mean * mean + 1e-5f);
  float4 lg = ((const float4*)flg)[t], lb = ((const float4*)flb)[t];
  bf16x4 q;
  q[0] = (bf16)gelu_exact((f0 - mean) * rsig * lg.x + lb.x);
  q[1] = (bf16)gelu_exact((f1 - mean) * rsig * lg.y + lb.y);
  q[2] = (bf16)gelu_exact((f2 - mean) * rsig * lg.z + lb.z);
  q[3] = (bf16)gelu_exact((f3 - mean) * rsig * lg.w + lb.w);
  ((bf16x4*)gout)[(size_t)tok * 256 + t] = q;
}

// ---------------------------------------------------------------------------
// reduce_oln: x1 = x + (op0 + op1) + out_b  (out-proj split-K partials),
// out0 = x1 + mlp_b2 (pre-init for MLP2 reduce), ln2 = bf16(LN(x1)).
// ---------------------------------------------------------------------------
__global__ __launch_bounds__(256) void reduce_oln(
    const float* __restrict__ part, const float* __restrict__ x,
    const float* __restrict__ outb, const float* __restrict__ b2,
    const float* __restrict__ g, const float* __restrict__ bb,
    float* __restrict__ out0, bf16* __restrict__ ln2) {
  __shared__ float red[8];
  int tok = blockIdx.x, t = threadIdx.x;
  size_t base = (size_t)tok * 256 + t;            // float4 index
  const size_t S = (size_t)4096 * 256;            // float4s per partial
  float4 p0 = ((const float4*)part)[base];
  float4 p1 = ((const float4*)part)[base + S];
  float4 xv = ((const float4*)x)[base];
  float4 ob = ((const float4*)outb)[t];
  float v0 = xv.x + p0.x + p1.x + ob.x;
  float v1 = xv.y + p0.y + p1.y + ob.y;
  float v2 = xv.z + p0.z + p1.z + ob.z;
  float v3 = xv.w + p0.w + p1.w + ob.w;
  float s = v0 + v1 + v2 + v3;
  float ss = v0 * v0 + v1 * v1 + v2 * v2 + v3 * v3;
  block_reduce2(s, ss, red, t);
  float mean = s * (1.0f / 1024.0f);
  float rsig = rsqrtf(ss * (1.0f / 1024.0f) - mean * mean + 1e-5f);
  float4 g4 = ((const float4*)g)[t], bb4 = ((const float4*)bb)[t];
  bf16x4 o;
  o[0] = (bf16)((v0 - mean) * rsig * g4.x + bb4.x);
  o[1] = (bf16)((v1 - mean) * rsig * g4.y + bb4.y);
  o[2] = (bf16)((v2 - mean) * rsig * g4.z + bb4.z);
  o[3] = (bf16)((v3 - mean) * rsig * g4.w + bb4.w);
  ((bf16x4*)ln2)[base] = o;
  float4 b24 = ((const float4*)b2)[t];
  float4 ov;
  ov.x = v0 + b24.x; ov.y = v1 + b24.y; ov.z = v2 + b24.z; ov.w = v3 + b24.w;
  ((float4*)out0)[base] = ov;
}

// ---------------------------------------------------------------------------
// 256x256 8-wave BK=64 GEMM, counted-vmcnt single-barrier phase pipeline
// (R3 structure, R7 B-reg reuse, R8-confirmed 1-barrier).
// ---------------------------------------------------------------------------
#define PHASE_LOADS(MH, NH, LA, LB, BFR)                                      \
    if (LA) {                                                                 \
      _Pragma("unroll") for (int ml = 0; ml < 4; ++ml) {                      \
        _Pragma("unroll") for (int ks = 0; ks < 2; ++ks) {                    \
          const int rr = ml * 16 + lm;                                        \
          const int cc = (((ks * 4 + quad) ^ (lm & 7)) << 3);                 \
          af[ml][ks] = *(const bf16x8*)&As[bsel][MH][wm][rr][cc];             \
        }                                                                     \
      }                                                                       \
    }                                                                         \
    if (LB) {                                                                 \
      _Pragma("unroll") for (int nl = 0; nl < 2; ++nl) {                      \
        _Pragma("unroll") for (int ks = 0; ks < 2; ++ks) {                    \
          const int rr = nl * 16 + lm;                                        \
          const int cc = (((ks * 4 + quad) ^ (lm & 7)) << 3);                 \
          BFR[nl][ks] = *(const bf16x8*)&Bs[bsel][NH][wn][rr][cc];            \
        }                                                                     \
      }                                                                       \
    }

#define PHASE_MFMA(MH, NH, BFR)                                               \
    _Pragma("unroll") for (int ks = 0; ks < 2; ++ks) {                        \
      _Pragma("unroll") for (int ml = 0; ml < 4; ++ml) {                      \
        _Pragma("unroll") for (int nl = 0; nl < 2; ++nl) {                    \
          acc[(MH)*4 + ml][(NH)*2 + nl] = mfma16(                             \
              af[ml][ks], BFR[nl][ks], acc[(MH)*4 + ml][(NH)*2 + nl]);        \
        }                                                                     \
      }                                                                       \
    }

#define PHASE(MH, NH, LA, LB, BFR, STAGE_STMT, WAIT_STMT)                     \
  do {                                                                        \
    PHASE_LOADS(MH, NH, LA, LB, BFR)                                          \
    STAGE_STMT;                                                               \
    WAIT_STMT;                                                                \
    hard_barrier();                                                           \
    __builtin_amdgcn_s_setprio(1);                                            \
    PHASE_MFMA(MH, NH, BFR)                                                   \
    __builtin_amdgcn_s_setprio(0);                                            \
  } while (0)

template <class Epi>
__global__ __launch_bounds__(512, 2) void gemm256(
    const bf16* __restrict__ A, const bf16* __restrict__ Bt,
    int lda, int ldb, int K, int kstride, int nbx, int nblk, int rowoffz,
    Epi epi) {
  __shared__ __align__(16) bf16 As[2][2][2][64][64];  // [buf][mh][wm][r][k]
  __shared__ __align__(16) bf16 Bs[2][2][4][32][64];  // [buf][nh][wn][r][k]

  const int tid = threadIdx.x;
  const int lane = tid & 63, w = tid >> 6;         // 8 waves
  const int quad = lane >> 4, lm = lane & 15;
  const int wm = w >> 2, wn = w & 3;               // 2x4 wave grid

  // split-K decode + bijective XCD swizzle (all grids are %8==0)
  const int kz = blockIdx.x / nblk;
  const int bid = blockIdx.x - kz * nblk;
  const int swz = (nblk & 7) ? bid : ((bid & 7) * (nblk >> 3) + (bid >> 3));
  const int tm = swz / nbx, tn = swz - tm * nbx;
  const int m0 = tm << 8, n0 = tn << 8;
  const int rowoff = kz * rowoffz;
  A += (size_t)kz * kstride;
  Bt += (size_t)kz * kstride;

  const bf16* Abase = A + (size_t)m0 * lda;
  const bf16* Bbase = Bt + (size_t)n0 * ldb;

  // one half-tile = 16 KiB = 2 global_load_lds per wave (1 KiB each)
  auto stageA = [&](int b, int mh, int kt) {
#pragma unroll
    for (int j = 0; j < 2; ++j) {
      const int q = (w * 2 + j) * 64 + lane;       // chunk id 0..1023
      const int wm2 = q >> 9, rr = (q >> 3) & 63, c = q & 7;
      async_load16(Abase + (size_t)(wm2 * 128 + mh * 64 + rr) * lda +
                       (size_t)kt * 64 + ((c ^ (rr & 7)) << 3),
                   (char*)&As[b][mh][0][0][0] + (w * 2 + j) * 1024);
    }
  };
  auto stageB = [&](int b, int nh, int kt) {
#pragma unroll
    for (int j = 0; j < 2; ++j) {
      const int q = (w * 2 + j) * 64 + lane;
      const int wn4 = q >> 8, rr = (q >> 3) & 31, c = q & 7;
      async_load16(Bbase + (size_t)(wn4 * 64 + nh * 32 + rr) * ldb +
                       (size_t)kt * 64 + ((c ^ (rr & 7)) << 3),
                   (char*)&Bs[b][nh][0][0][0] + (w * 2 + j) * 1024);
    }
  };

  f32x4 acc[8][4];
#pragma unroll
  for (int i = 0; i < 8; ++i)
#pragma unroll
    for (int j = 0; j < 4; ++j) {
      acc[i][j][0] = 0.f; acc[i][j][1] = 0.f;
      acc[i][j][2] = 0.f; acc[i][j][3] = 0.f;
    }
  bf16x8 af[4][2], bfrA[2][2], bfrB[2][2];

  // prologue: tile0 fully + tile1's (Ah0,Bh1) = the "p2/p3 of t=-1" slots.
  stageA(0, 0, 0);  // Ah0(0)
  stageB(0, 1, 0);  // Bh1(0)
  stageA(0, 1, 0);  // Ah1(0)
  stageB(0, 0, 0);  // Bh0(0)
  stageA(1, 0, 1);  // Ah0(1)
  stageB(1, 1, 1);  // Bh1(1)
  asm volatile("s_waitcnt vmcnt(4)" ::: "memory");  // tile0 resident
  hard_barrier();

  const int nt = K >> 6;
  int bsel = 0;
  for (int t = 0; t < nt; ++t, bsel ^= 1) {
    PHASE(0, 0, 1, 1, bfrA, { if (t + 1 < nt) stageA(bsel ^ 1, 1, t + 1); }, {});
    PHASE(0, 1, 0, 1, bfrB, { if (t + 1 < nt) stageB(bsel ^ 1, 0, t + 1); }, {});
    PHASE(1, 1, 1, 0, bfrB, { if (t + 2 < nt) stageA(bsel, 0, t + 2); }, {});
    PHASE(1, 0, 0, 0, bfrA, { if (t + 2 < nt) stageB(bsel, 1, t + 2); },
          {
            if (t + 2 < nt) {
              asm volatile("s_waitcnt vmcnt(4)" ::: "memory");
            } else if (t + 1 < nt) {
              asm volatile("s_waitcnt vmcnt(0)" ::: "memory");
            }
          });
  }

#pragma unroll
  for (int mi = 0; mi < 8; ++mi)
#pragma unroll
    for (int ni = 0; ni < 4; ++ni)
      epi(rowoff + m0 + wm * 128 + mi * 16 + quad * 4,
          n0 + wn * 64 + ni * 16 + lm, acc[mi][ni]);
}

// out += part0 + part1 + part2 + part3  (out pre-initialized x1 + mlp_b2)
__global__ __launch_bounds__(256) void reduce_mlp2(
    const float* __restrict__ part, float* __restrict__ out) {
  size_t i = (size_t)blockIdx.x * 256 + threadIdx.x;  // float4 index
  const float4* p = (const float4*)part;
  float4 o = ((const float4*)out)[i];
  const size_t S = (size_t)4096 * 256;  // float4s per partial
  float4 a = p[i], b = p[i + S], c = p[i + 2 * S], d = p[i + 3 * S];
  o.x += a.x + b.x + c.x + d.x;
  o.y += a.y + b.y + c.y + d.y;
  o.z += a.z + b.z + c.z + d.z;
  o.w += a.w + b.w + c.w + d.w;
  ((float4*)out)[i] = o;
}

// --------------------------- epilogue functors -----------------------------
// Qc carries log2e so flash softmax can use native exp2.
struct EpiQKV {
  const float* __restrict__ bias;
  bf16 *Qc, *Kc, *Vt;
  DEVINL void operator()(int row, int col, f32x4 v) const {
    int b = row >> 11, l = row & 2047;
    float bia = bias[col];
    if (col < 1024) {
      int h = col >> 6, d = col & 63;
      bf16* p = Qc + (size_t)(((b << 4) + h) * 2048 + l) * 128 + d;
#pragma unroll
      for (int r = 0; r < 4; ++r) p[r * 128] = (bf16)((v[r] + bia) * (0.125f * LOG2E));
    } else if (col < 2048) {
      int c2 = col - 1024, h = c2 >> 6, d = c2 & 63;
      bf16* p = Kc + (size_t)(((b << 4) + h) * 2048 + l) * 128 + d;
#pragma unroll
      for (int r = 0; r < 4; ++r) p[r * 128] = (bf16)(v[r] + bia);
    } else {
      int c2 = col - 2048, h = c2 >> 6, d = c2 & 63;
      bf16x4 pk;
#pragma unroll
      for (int r = 0; r < 4; ++r) pk[r] = (bf16)(v[r] + bia);
      *(bf16x4*)(Vt + (size_t)(((b << 4) + h) * 64 + d) * 2048 + l) = pk;
    }
  }
};

struct EpiQBKB {
  const float* __restrict__ bias;
  const float* __restrict__ fs;
  bf16 *Qc, *Kc;
  DEVINL void operator()(int row, int col, f32x4 v) const {
    int b = row >> 11, l = row & 2047;
    float bia = bias[col];
    if (col < 1024) {
      int h = col >> 6, d = col & 63;
      float sc = fs[0] * LOG2E;
      bf16* p = Qc + (size_t)(((b << 4) + h) * 2048 + l) * 128 + 64 + d;
#pragma unroll
      for (int r = 0; r < 4; ++r) p[r * 128] = (bf16)((v[r] + bia) * sc);
    } else {
      int c2 = col - 1024, h = c2 >> 6, d = c2 & 63;
      bf16* p = Kc + (size_t)(((b << 4) + h) * 2048 + l) * 128 + 64 + d;
#pragma unroll
      for (int r = 0; r < 4; ++r) p[r * 128] = (bf16)(v[r] + bia);
    }
  }
};

struct EpiMLP1 {
  const float* __restrict__ bias;
  bf16* hbf;
  DEVINL void operator()(int row, int col, f32x4 v) const {
    float bia = bias[col];
#pragma unroll
    for (int r = 0; r < 4; ++r)
      hbf[(size_t)(row + r) * 4096 + col] = (bf16)gelu_exact(v[r] + bia);
  }
};

// split-K partials: row already carries kz*4096 offset.
struct EpiPart {
  float* part;
  DEVINL void operator()(int row, int col, f32x4 v) const {
#pragma unroll
    for (int r = 0; r < 4; ++r)
      part[(size_t)(row + r) * 1024 + col] = v[r];
  }
};

// ---------------------------------------------------------------------------
// Flash attention v6.2: QBLK=256, Ps stride 64, T5 setprio.
// ---------------------------------------------------------------------------
#define PSS 64  // Ps row stride in bf16

__global__ __launch_bounds__(512, 2) void flash_kernel(
    const bf16* __restrict__ Qc, const bf16* __restrict__ Kcp,
    const bf16* __restrict__ Vt, bf16* __restrict__ Obf) {
  __shared__ bf16 KsA[64 * 128];
  __shared__ bf16 KsB[64 * 128];
  __shared__ bf16 VsA[64 * 64];
  __shared__ bf16 VsB[64 * 64];
  __shared__ bf16 Ps[256 * PSS];  // P^T rows=q; per-wave private rows

  const int tid = threadIdx.x, lane = tid & 63, w = tid >> 6;  // w 0..7
  const int quad = lane >> 4, lm = lane & 15;
  const int id = blockIdx.x;
  const int bh = id & 31, qt = id >> 5;  // qt 0..7
  const int b = bh >> 4, h = bh & 15;
  const int qrw = w * 32;                // wave's first q row in 256-row tile

  const bf16* Kg0 = Kcp + (size_t)bh * 2048 * 128;
  const bf16* Vg0 = Vt + (size_t)bh * 64 * 2048;

  auto stage = [&](int kv, bf16* Kdst, bf16* Vdst) {
    const bf16* Kg = Kg0 + (size_t)kv * 64 * 128;
#pragma unroll
    for (int i = 0; i < 2; ++i) {
      int ch = i * 512 + tid, key = ch >> 4, c = (ch & 15) ^ (key & 7);
      async_load16(Kg + (size_t)key * 128 + c * 8,
                   (char*)Kdst + (i * 512 + w * 64) * 16);
    }
    {
      int d = tid >> 3, c = (tid & 7) ^ (d & 7);
      async_load16(Vg0 + (size_t)d * 2048 + kv * 64 + c * 8,
                   (char*)Vdst + (w * 64) * 16);
    }
  };

  stage(0, KsA, VsA);  // issue tile-0 DMA first; Q reg loads overlap it

  // ---- Q fragments, ONCE, direct global -> registers ----
  const bf16* Qg = Qc + ((size_t)bh * 2048 + qt * 256) * 128;
  bf16x8 qf[2][4];
#pragma unroll
  for (int qh = 0; qh < 2; ++qh)
#pragma unroll
    for (int ks = 0; ks < 4; ++ks)
      qf[qh][ks] = *(const bf16x8*)(Qg + (size_t)(qrw + qh * 16 + lm) * 128 +
                                    (ks * 4 + quad) * 8);

  float m_run[2] = {-3.0e38f, -3.0e38f};
  float l_lane[2] = {0.f, 0.f};
  f32x4 o_acc[2][4];
#pragma unroll
  for (int qh = 0; qh < 2; ++qh)
#pragma unroll
    for (int nf = 0; nf < 4; ++nf) {
      o_acc[qh][nf][0] = 0.f; o_acc[qh][nf][1] = 0.f;
      o_acc[qh][nf][2] = 0.f; o_acc[qh][nf][3] = 0.f;
    }

  for (int kv = 0; kv < 32; ++kv) {
    const bf16* Kcur = (kv & 1) ? KsB : KsA;
    const bf16* Vcur = (kv & 1) ? VsB : VsA;
    __syncthreads();  // drains stage(kv); prev reads of other buf done
    if (kv + 1 < 32)
      stage(kv + 1, (kv & 1) ? KsA : KsB, (kv & 1) ? VsA : VsB);

    // ---- S^T = K · Q^T : 64 keys x 32 q (2 halves share ak reads) ----
    f32x4 sa[2][4];
#pragma unroll
    for (int qh = 0; qh < 2; ++qh)
#pragma unroll
      for (int nk = 0; nk < 4; ++nk) {
        sa[qh][nk][0] = 0.f; sa[qh][nk][1] = 0.f;
        sa[qh][nk][2] = 0.f; sa[qh][nk][3] = 0.f;
      }
    __builtin_amdgcn_s_setprio(1);
#pragma unroll
    for (int ks = 0; ks < 4; ++ks) {
      bf16x8 ak[4];
#pragma unroll
      for (int nk = 0; nk < 4; ++nk) {
        int key = nk * 16 + lm;
        int pos = (ks * 4 + quad) ^ (key & 7);
        ak[nk] = *(const bf16x8*)(Kcur + key * 128 + pos * 8);
      }
#pragma unroll
      for (int nk = 0; nk < 4; ++nk) {
        sa[0][nk] = mfma16(ak[nk], qf[0][ks], sa[0][nk]);
        sa[1][nk] = mfma16(ak[nk], qf[1][ks], sa[1][nk]);
      }
    }
    __builtin_amdgcn_s_setprio(0);

#pragma unroll
    for (int qh = 0; qh < 2; ++qh) {
      // ---- online softmax (exp2 domain); lane owns column qrw+qh*16+lm ----
      float mx = fmaxf(fmaxf(sa[qh][0][0], sa[qh][0][1]), sa[qh][0][2]);
      mx = fmaxf(fmaxf(mx, sa[qh][0][3]), sa[qh][1][0]);
      mx = fmaxf(fmaxf(mx, sa[qh][1][1]), sa[qh][1][2]);
      mx = fmaxf(fmaxf(mx, sa[qh][1][3]), sa[qh][2][0]);
      mx = fmaxf(fmaxf(mx, sa[qh][2][1]), sa[qh][2][2]);
      mx = fmaxf(fmaxf(mx, sa[qh][2][3]), sa[qh][3][0]);
      mx = fmaxf(fmaxf(mx, sa[qh][3][1]), sa[qh][3][2]);
      mx = fmaxf(mx, sa[qh][3][3]);
      mx = fmaxf(mx, __shfl_xor(mx, 16));
      mx = fmaxf(mx, __shfl_xor(mx, 32));
      // defer-max: only rescale when some lane's max grew past m_run + 8.
      if (__any(mx > m_run[qh] + 8.0f)) {
        float mnew = fmaxf(m_run[qh], mx);
        float alpha = fast_exp2(m_run[qh] - mnew);
        m_run[qh] = mnew;
        l_lane[qh] *= alpha;
#pragma unroll
        for (int nf = 0; nf < 4; ++nf) {
          o_acc[qh][nf][0] *= alpha; o_acc[qh][nf][1] *= alpha;
          o_acc[qh][nf][2] *= alpha; o_acc[qh][nf][3] *= alpha;
        }
      }
      float rs = 0.f;
#pragma unroll
      for (int nk = 0; nk < 4; ++nk)
#pragma unroll
        for (int rg = 0; rg < 4; ++rg) {
          float pv = fast_exp2(sa[qh][nk][rg] - m_run[qh]);
          sa[qh][nk][rg] = pv;
          rs += pv;
        }
      l_lane[qh] += rs;  // cross-quad reduce deferred past the kv loop

      // ---- write P^T rows (wave-private; same-wave readback) ----
      int qr = qrw + qh * 16 + lm;
#pragma unroll
      for (int nk = 0; nk < 4; ++nk) {
        int c16 = 2 * nk + (quad >> 1);
        int cs = c16 ^ (lm & 7);
        bf16x4 pk;
        pk[0] = (bf16)sa[qh][nk][0]; pk[1] = (bf16)sa[qh][nk][1];
        pk[2] = (bf16)sa[qh][nk][2]; pk[3] = (bf16)sa[qh][nk][3];
        *(bf16x4*)(Ps + qr * PSS + cs * 8 + (quad & 1) * 4) = pk;
      }
    }

    // ---- O^T += V^T · P^T (vb reads shared across both q-halves) ----
#pragma unroll
    for (int ks = 0; ks < 2; ++ks) {
      bf16x8 vb[4], pa[2];
#pragma unroll
      for (int nf = 0; nf < 4; ++nf) {
        int d = nf * 16 + lm;
        int cs = (ks * 4 + quad) ^ (d & 7);
        vb[nf] = *(const bf16x8*)(Vcur + d * 64 + cs * 8);
      }
#pragma unroll
      for (int qh = 0; qh < 2; ++qh) {
        int qr = qrw + qh * 16 + lm;
        int cs = (ks * 4 + quad) ^ (lm & 7);
        pa[qh] = *(const bf16x8*)(Ps + qr * PSS + cs * 8);
      }
      __builtin_amdgcn_s_setprio(1);
#pragma unroll
      for (int qh = 0; qh < 2; ++qh)
#pragma unroll
        for (int nf = 0; nf < 4; ++nf)
          o_acc[qh][nf] = mfma16(vb[nf], pa[qh], o_acc[qh][nf]);
      __builtin_amdgcn_s_setprio(0);
    }
  }

  // ---- normalize (in-lane after final cross-quad l reduce) + write O ----
#pragma unroll
  for (int qh = 0; qh < 2; ++qh) {
    float lt = l_lane[qh];
    lt += __shfl_xor(lt, 16);
    lt += __shfl_xor(lt, 32);
    float inv = 1.0f / lt;
    int l = qt * 256 + qrw + qh * 16 + lm;
#pragma unroll
    for (int nf = 0; nf < 4; ++nf) {
      bf16x4 ov;
#pragma unroll
      for (int rg = 0; rg < 4; ++rg) ov[rg] = (bf16)(o_acc[qh][nf][rg] * inv);
      int d = h * 64 + nf * 16 + quad * 4;
      *(bf16x4*)(Obf + ((size_t)b * 2048 + l) * 1024 + d) = ov;
    }
  }
}

// ---------------------------------------------------------------------------
extern "C" void kernel_launch(void* const* d_in, const int* in_sizes, int n_in,
                              void* d_out, int out_size, void* d_ws, size_t ws_size,
                              hipStream_t stream) {
  (void)in_sizes; (void)n_in; (void)out_size; (void)ws_size;
  const float* x      = (const float*)d_in[0];
  const float* fd     = (const float*)d_in[1];
  const float* qkv_w  = (const float*)d_in[2];
  const float* qkv_b  = (const float*)d_in[3];
  const float* fp_w1  = (const float*)d_in[4];
  const float* fp_b1  = (const float*)d_in[5];
  const float* fp_ln_g= (const float*)d_in[6];
  const float* fp_ln_b= (const float*)d_in[7];
  const float* fp_w2  = (const float*)d_in[8];
  const float* fp_b2  = (const float*)d_in[9];
  const float* wq_w   = (const float*)d_in[10];
  const float* wq_b   = (const float*)d_in[11];
  const float* wk_w   = (const float*)d_in[12];
  const float* wk_b   = (const float*)d_in[13];
  const float* out_w  = (const float*)d_in[14];
  const float* out_b  = (const float*)d_in[15];
  const float* n1_g   = (const float*)d_in[16];
  const float* n1_b   = (const float*)d_in[17];
  const float* n2_g   = (const float*)d_in[18];
  const float* n2_b   = (const float*)d_in[19];
  const float* mlp_w1 = (const float*)d_in[20];
  const float* mlp_b1 = (const float*)d_in[21];
  const float* mlp_w2 = (const float*)d_in[22];
  const float* mlp_b2 = (const float*)d_in[23];
  const float* fscale = (const float*)d_in[24];
  float* out = (float*)d_out;

  char* p = (char*)d_ws;
  auto take = [&](size_t n) { char* r = p; p += (n + 255) & ~(size_t)255; return r; };
  bf16* xn_bf  = (bf16*)take((size_t)4096 * 1024 * 2);
  bf16* g_bf   = (bf16*)take((size_t)4096 * 1024 * 2);
  bf16* Qc     = (bf16*)take((size_t)32 * 2048 * 128 * 2);
  bf16* Kc     = (bf16*)take((size_t)32 * 2048 * 128 * 2);
  bf16* Vt     = (bf16*)take((size_t)32 * 64 * 2048 * 2);
  bf16* o_bf   = (bf16*)take((size_t)4096 * 1024 * 2);
  bf16* ln2_bf = (bf16*)take((size_t)4096 * 1024 * 2);
  bf16* h_bf   = (bf16*)take((size_t)4096 * 4096 * 2);
  bf16* qkv_wt = (bf16*)take((size_t)3072 * 1024 * 2);
  bf16* out_wt = (bf16*)take((size_t)1024 * 1024 * 2);
  bf16* w1t    = (bf16*)take((size_t)4096 * 1024 * 2);
  bf16* w2t    = (bf16*)take((size_t)1024 * 4096 * 2);
  bf16* wqk2t  = (bf16*)take((size_t)2048 * 1024 * 2);
  float* bqk   = (float*)take((size_t)2048 * 4);

  // MLP2 partials (4 x 16 MB fp32) alias the dead xn/g/Qc/Kc/Vt region.
  float* part = (float*)xn_bf;
  // out-proj partials (2 x 16 MB fp32) alias h_bf (written later by MLP1;
  // opart is dead before MLP1 runs).
  float* opart = (float*)h_bf;

  dim3 b256(256), b512(512);

  // prec_qk (256) + 4 weight transposes (12288) + ln1 (4096) in one launch
  pre_kernel<<<dim3(16640), b256, 0, stream>>>(
      fp_w2, fp_b2, wq_w, wq_b, wk_w, wk_b, wqk2t, bqk,
      qkv_w, out_w, mlp_w1, mlp_w2, qkv_wt, out_wt, w1t, w2t,
      x, fd, n1_g, n1_b, fp_w1, fp_b1, fp_ln_g, fp_ln_b, xn_bf, g_bf);

  // QKV: M=4096 N=3072 K=1024 -> 12x16 = 192 blocks
  gemm256<<<dim3(192), b512, 0, stream>>>(xn_bf, qkv_wt, 1024, 1024, 1024, 0,
                                          12, 192, 0, EpiQKV{qkv_b, Qc, Kc, Vt});
  // QB/KB: M=4096 N=2048 K=1024 -> 8x16 = 128 blocks
  gemm256<<<dim3(128), b512, 0, stream>>>(g_bf, wqk2t, 1024, 1024, 1024, 0,
                                          8, 128, 0, EpiQBKB{bqk, fscale, Qc, Kc});
  // flash: 32 bh x 8 q-tiles (QBLK=256) = 256 blocks
  flash_kernel<<<dim3(256), dim3(512), 0, stream>>>(Qc, Kc, Vt, o_bf);

  // out-proj split-K=2: per kz 16x4 = 64 blocks; partials -> reduce_oln.
  gemm256<<<dim3(128), b512, 0, stream>>>(o_bf, out_wt, 1024, 1024, 512, 512,
                                          4, 64, 4096, EpiPart{opart});
  // residual + bias + LN2 + out0-preinit fused (out0 = x1 + mlp_b2)
  reduce_oln<<<dim3(4096), b256, 0, stream>>>(opart, x, out_b, mlp_b2,
                                              n2_g, n2_b, out, ln2_bf);
  // MLP1: M=4096 N=4096 K=1024 -> 16x16 = 256 blocks (v1, confirmed)
  gemm256<<<dim3(256), b512, 0, stream>>>(ln2_bf, w1t, 1024, 1024, 1024, 0,
                                          16, 256, 0, EpiMLP1{mlp_b1, h_bf});
  // MLP2 split-K=4: per split M=4096 N=1024 K=1024 -> 4x16 = 64 blocks, x4
  gemm256<<<dim3(256), b512, 0, stream>>>(h_bf, w2t, 4096, 4096, 1024, 1024,
                                          4, 64, 4096, EpiPart{part});
  reduce_mlp2<<<dim3(4096), b256, 0, stream>>>(part, out);
}